// Round 6
// baseline (88.072 us; speedup 1.0000x reference)
//
#include <hip/hip_runtime.h>

#define K      32
#define TPB    256
#define NB     2048                 // main-kernel blocks: 2048*256*4 = N
#define EPT    4                    // elements per thread (grid-stride)
#define NTOT   (32 * 64 * 1024)     // 2,097,152
#define STRIDE (TPB * NB)           // 524288

typedef float v2f __attribute__((ext_vector_type(2)));

__device__ __forceinline__ float wave_reduce_sum(float v) {
#pragma unroll
  for (int m = 1; m < 64; m <<= 1) v += __shfl_xor(v, m, 64);
  return v;
}

__device__ __forceinline__ float to_sgpr(float v) {
  return __int_as_float(__builtin_amdgcn_readfirstlane(__float_as_int(v)));
}

// Register control is STRUCTURAL (no launch_bounds caps — R0/R2 spilled;
// no full e-unroll — R4 ballooned to 256 VGPRs). 'unroll 1' e-loop proven R5.
// This round: v2f (ext_vector_type(2)) arithmetic so the backend emits
// VOP3P v_pk_{add,mul,min,fma}_f32 — halves VALU issue per (elem,k).
// abs trick: Ch<0 so Ch*|d| = min(Ch*d, -(Ch*d)) -> pk_min with neg modifier
// (VOP3P has no abs modifier).
__global__ __launch_bounds__(TPB)
void ssq_main(const float* __restrict__ x, const float* __restrict__ bins,
              float* __restrict__ out, float* __restrict__ partials) {
  const int tid  = threadIdx.x;
  const int base = blockIdx.x * TPB + tid;

  // wave-uniform -> SGPRs
  float binv[K];
#pragma unroll
  for (int k = 0; k < K; ++k) binv[k] = to_sgpr(bins[k]);
  float binsum = 0.f;
#pragma unroll
  for (int k = 0; k < K; ++k) binsum += binv[k];
  const float epsb = 1e-10f * binsum;    // eps * sum(bins) term of bit_code

  v2f binv2[K / 2];
#pragma unroll
  for (int i = 0; i < K / 2; ++i) binv2[i] = (v2f){binv[2 * i], binv[2 * i + 1]};

  float xs[EPT];
#pragma unroll
  for (int e = 0; e < EPT; ++e) xs[e] = x[base + e * STRIDE];

  v2f sAcc2[K / 2];
#pragma unroll
  for (int i = 0; i < K / 2; ++i) sAcc2[i] = (v2f){0.f, 0.f};
  float q = 0.f;

  const float Ch = -7.213475204444817f;   // 0.5 * ALPHA * log2(e)
  const v2f Ch2 = {Ch, Ch};

#pragma unroll 1
  for (int e = 0; e < EPT; ++e) {
    const float xv = xs[e];
    const v2f xv2 = {xv, xv};
    v2f t2[K / 2];                        // lives only inside this iteration
    v2f s2a = {0.f, 0.f}, s2b = {0.f, 0.f};
    v2f h2a = {0.f, 0.f}, h2b = {0.f, 0.f};
    v2f b2a = {0.f, 0.f}, b2b = {0.f, 0.f};
#pragma unroll
    for (int i = 0; i < K / 2; i += 2) {
      v2f d0 = xv2 - binv2[i];
      v2f d1 = xv2 - binv2[i + 1];
      v2f p0 = d0 * Ch2;
      v2f p1 = d1 * Ch2;
      v2f m0 = __builtin_elementwise_min(p0, -p0);   // = Ch*|d| (Ch<0)
      v2f m1 = __builtin_elementwise_min(p1, -p1);
      v2f h0 = {__builtin_amdgcn_exp2f(m0.x), __builtin_amdgcn_exp2f(m0.y)};
      v2f h1 = {__builtin_amdgcn_exp2f(m1.x), __builtin_amdgcn_exp2f(m1.y)};
      v2f t0 = h0 * h0;
      v2f t1 = h1 * h1;
      t2[i]     = t0;
      t2[i + 1] = t1;
      s2a += t0; s2b += t1;
      h2a += h0; h2b += h1;
      b2a += t0 * binv2[i];       // contracts to v_pk_fma_f32
      b2b += t1 * binv2[i + 1];
    }
    const v2f sv2 = (s2a + s2b);
    const v2f hv2 = (h2a + h2b);
    const v2f bv2 = (b2a + b2b);
    const float s    = sv2.x + sv2.y;
    const float hsum = hv2.x + hv2.y;
    const float bnum = bv2.x + bv2.y;
    const float inv  = __builtin_amdgcn_rcpf(s);
    q = fmaf(hsum, __builtin_amdgcn_rsqf(s), q);   // sum_k sqrt(a) = rsqrt(s)*sum h
    out[base + e * STRIDE] = fmaf(bnum, inv, epsb);
    const v2f inv2 = {inv, inv};
#pragma unroll
    for (int i = 0; i < K / 2; ++i) sAcc2[i] += t2[i] * inv2;  // pk_fma
  }

  // block reduction: wave shuffle -> LDS -> one partial per counter per block
  __shared__ float red[4][K + 1];
  const int lane = tid & 63, wv = tid >> 6;
#pragma unroll
  for (int k = 0; k < K; ++k) {
    float v = wave_reduce_sum(sAcc2[k >> 1][k & 1]);
    if (lane == 0) red[wv][k] = v;
  }
  {
    float v = wave_reduce_sum(q);
    if (lane == 0) red[wv][K] = v;
  }
  __syncthreads();
  if (tid < K + 1) {
    float v = red[0][tid] + red[1][tid] + red[2][tid] + red[3][tid];
    partials[tid * NB + blockIdx.x] = v;   // written exactly once, no init needed
  }
}

// 33 blocks: block c reduces partials[c*NB .. c*NB+NB) -> sums[c]
__global__ __launch_bounds__(TPB)
void ssq_reduce(const float* __restrict__ partials, float* __restrict__ sums) {
  const float* p = partials + blockIdx.x * NB;
  const int tid  = threadIdx.x;
  float s = 0.f;
#pragma unroll
  for (int j = 0; j < NB / TPB; ++j) s += p[tid + j * TPB];
  s = wave_reduce_sum(s);
  __shared__ float red[4];
  if ((tid & 63) == 0) red[tid >> 6] = s;
  __syncthreads();
  if (tid == 0) sums[blockIdx.x] = red[0] + red[1] + red[2] + red[3];
}

// one wave: entropy over 32 p_k + quant mean + tails
__global__ void ssq_final(const float* __restrict__ sums, float* __restrict__ out) {
  const int lane = threadIdx.x;
  float e = 0.f;
  if (lane < K) {
    float p = sums[lane] * (1.0f / (float)NTOT) + 1e-10f;  // eps folded in here
    e = -p * __logf(p);
  }
  e = wave_reduce_sum(e);
  if (lane == 0) {
    out[NTOT + 0] = e;                              // code entropy
    out[NTOT + 1] = 0.f;                            // TAU
    out[NTOT + 2] = sums[K] * (1.0f / (float)NTOT); // quant loss
    out[NTOT + 3] = 0.f;                            // TAU2
  }
}

extern "C" void kernel_launch(void* const* d_in, const int* in_sizes, int n_in,
                              void* d_out, int out_size, void* d_ws, size_t ws_size,
                              hipStream_t stream) {
  const float* x    = (const float*)d_in[0];
  const float* bins = (const float*)d_in[1];
  float* out        = (float*)d_out;
  float* partials   = (float*)d_ws;                 // (K+1)*NB floats = 264 KB
  float* sums       = partials + (K + 1) * NB;      // 33 floats

  ssq_main  <<<NB,    TPB, 0, stream>>>(x, bins, out, partials);
  ssq_reduce<<<K + 1, TPB, 0, stream>>>(partials, sums);
  ssq_final <<<1,     64,  0, stream>>>(sums, out);
}